// Round 8
// baseline (4211.449 us; speedup 1.0000x reference)
//
#include <hip/hip_runtime.h>
#include <math.h>

#define B64 64
#define H 1024
#define DD 8
#define ENC 96
#define HOR 336
#define TT 432
#define NSTEP 431
#define NBLK 256
#define KS0 32      // K=1024 in 32-wide chunks
#define KS1 64      // K=2048

typedef __attribute__((ext_vector_type(8))) short short8;
typedef __attribute__((ext_vector_type(4))) float f32x4;
typedef __attribute__((ext_vector_type(4))) unsigned int u32x4;
typedef unsigned long long ull;

__device__ __forceinline__ unsigned short f2bf(float x) {
    union { float f; unsigned u; } v; v.f = x;
    unsigned r = v.u + 0x7fffu + ((v.u >> 16) & 1u);
    return (unsigned short)(r >> 16);
}
__device__ __forceinline__ float sigm(float x) {
    return __builtin_amdgcn_rcpf(1.0f + __expf(-x));
}
__device__ __forceinline__ float ftanh(float x) {
    float e = __expf(fminf(x, 10.0f) * 2.0f);   // clamp: avoid inf/inf
    return (e - 1.0f) * __builtin_amdgcn_rcpf(e + 1.0f);
}

// Agent-coherent 16B load/store via one dwordx4 (sc0 sc1) — halves coherent
// transaction count vs 2x8B atomics. Callers MUST kwait() before using loads.
__device__ __forceinline__ short8 cload16(const unsigned short* p) {
    u32x4 v;
    asm volatile("global_load_dwordx4 %0, %1, off sc0 sc1"
                 : "=v"(v) : "v"(p) : "memory");
    union { u32x4 u; short8 s; } c; c.u = v; return c.s;
}
__device__ __forceinline__ void cstore16(unsigned short* p, ull lo, ull hi) {
    union { ull u[2]; u32x4 v; } c; c.u[0] = lo; c.u[1] = hi;
    asm volatile("global_store_dwordx4 %0, %1, off sc0 sc1"
                 :: "v"(p), "v"(c.v) : "memory");
}
__device__ __forceinline__ void kwait() {
    asm volatile("s_waitcnt vmcnt(0)" ::: "memory");
    __builtin_amdgcn_sched_barrier(0);      // guide rule 18: pin uses after wait
}

// ---------------- prep kernels (verified) ----------------

__global__ void zero_k(unsigned int* __restrict__ p, int n) {
    for (int i = blockIdx.x * 256 + threadIdx.x; i < n; i += gridDim.x * 256) p[i] = 0u;
}

__global__ void pack0_k(const float* __restrict__ w, unsigned short* __restrict__ dst) {
    const int total = 128 * 2 * KS0 * 64 * 8;
    for (int idx = blockIdx.x * 256 + threadIdx.x; idx < total; idx += gridDim.x * 256) {
        int j = idx & 7, lane = (idx >> 3) & 63, ks = (idx >> 9) & 31, nt = (idx >> 14) & 1, nb = idx >> 15;
        int rr = nt * 16 + (lane & 15);
        int row = nb * 8 + (rr >> 2) + 1024 * (rr & 3);
        int k = ks * 32 + ((lane >> 4) << 3) + j;
        dst[idx] = f2bf(w[row * 1024 + k]);
    }
}

__global__ void pack1_k(const float* __restrict__ wih, const float* __restrict__ whh,
                        unsigned short* __restrict__ dst) {
    const int total = 128 * 2 * KS1 * 64 * 8;
    for (int idx = blockIdx.x * 256 + threadIdx.x; idx < total; idx += gridDim.x * 256) {
        int j = idx & 7, lane = (idx >> 3) & 63, ks = (idx >> 9) & 63, nt = (idx >> 15) & 1, nb = idx >> 16;
        int rr = nt * 16 + (lane & 15);
        int row = nb * 8 + (rr >> 2) + 1024 * (rr & 3);
        int k = ks * 32 + ((lane >> 4) << 3) + j;
        float v = (k < 1024) ? wih[row * 1024 + k] : whh[row * 1024 + (k - 1024)];
        dst[idx] = f2bf(v);
    }
}

__global__ void pack2_k(const float* __restrict__ w, unsigned short* __restrict__ dst) {
    const int total = 2 * KS0 * 64 * 8;
    for (int idx = blockIdx.x * 256 + threadIdx.x; idx < total; idx += gridDim.x * 256) {
        int j = idx & 7, lane = (idx >> 3) & 63, ks = (idx >> 9) & 31, nt = (idx >> 14) & 1;
        int rr = nt * 16 + (lane & 15);
        int row = (rr >> 2) + 8 * (rr & 3);
        int k = ks * 32 + ((lane >> 4) << 3) + j;
        dst[idx] = f2bf(w[row * 1024 + k]);
    }
}

__global__ void copy_y_k(const float* __restrict__ inp, float* __restrict__ y) {
    const int total = B64 * HOR * DD;
    for (int i = blockIdx.x * 256 + threadIdx.x; i < total; i += gridDim.x * 256) {
        int b = i / (HOR * DD);
        int rem = i - b * (HOR * DD);
        y[i] = inp[b * (TT * DD) + ENC * DD + rem];
    }
}

__global__ void loss_k(const float* __restrict__ pred, const float* __restrict__ y,
                       float* __restrict__ loss) {
    __shared__ float part[256];
    int tid = threadIdx.x;
    int dd = tid & 7, cc = tid >> 3;
    float s = 0.f;
    for (int i = cc; i < B64 * HOR; i += 32) {
        float d = pred[i * 8 + dd] - y[i * 8 + dd];
        s += d * d;
    }
    part[tid] = s;
    __syncthreads();
    if (tid < 8) {
        float t = 0.f;
        for (int r = 0; r < 32; ++r) t += part[r * 8 + tid];
        loss[tid] = t / (float)(B64 * HOR);
    }
}

// ---- counting grid barrier: ONE MALL-resident atomic counter per domain ----
// arrive: tid0 drains its wave's publish stores (publish is wave-0-only), then
// atomicAdd(counter,1) — the RMW executes AT the MALL, keeping the line
// MALL-owned (no per-poll HBM refetch like the 128-flag sweep: R6's FETCH_SIZE
// showed ~250MB of poll traffic reaching HBM).
// wait: tid0 polls the single hot line until >= 128*ep; __syncthreads releases.
// Safety (monotone counting barrier): every arrive(ep) is program-ordered
// after wait(ep-1), so counter==128*ep first occurs when ALL blocks arrived
// ep times (induction; no early-arrive fast path in this schedule).
__device__ __forceinline__ void gbar_arrive(unsigned* cnt, unsigned) {
    if (threadIdx.x == 0) {
        __builtin_amdgcn_s_waitcnt(0x0f70);     // vmcnt(0)
        atomicAdd(cnt, 1u);
    }
}
__device__ __forceinline__ void gbar_wait(unsigned* cnt, unsigned ep) {
    if (threadIdx.x == 0) {
        const unsigned tgt = ep * 128u;
        while (__hip_atomic_load(cnt, __ATOMIC_RELAXED,
                                 __HIP_MEMORY_SCOPE_AGENT) < tgt) { }
    }
    __syncthreads();
}

// ---------------- persistent recurrence kernel ----------------
// Drain-overlapped schedule (per step, 2 barriers):
//  wait A   -> h0(t) visible
//  window A: load pa/pb = h0(t) (16B sc-loads); acc += MFMA(pa/pb, Wr1h0)
//            [acc carries the h1(t-1) half from the previous window-B tail];
//            reduce; P2 cell -> publish h1(t);
//            P1(t+1) GEMM on pa/pb -> red2   [h1 store-acks drain under this]
//            arrive B
//  wait B   -> h1(t) visible
//  window B: load qa/qb = h1(t); P3 GEMM (streamed Wr2) -> reduce; P3 cell ->
//            h2x/pred; P1 cell (red2 + wih0*x) -> publish h0(t+1);
//            acc = MFMA(qa/qb, Wr1h1)        [h0 store-acks drain under this]
//            arrive A
__global__ __launch_bounds__(256, 1) void persist_k(
    const unsigned short* __restrict__ Wp0,
    const unsigned short* __restrict__ Wp1,
    const unsigned short* __restrict__ Wp2,
    const float* __restrict__ wih0, const float* __restrict__ b0v,
    const float* __restrict__ b1v,
    const float* __restrict__ whh2, const float* __restrict__ b2v,
    const float* __restrict__ inp,
    unsigned short* __restrict__ H0a, unsigned short* __restrict__ H0b,
    unsigned short* __restrict__ H1a, unsigned short* __restrict__ H1b,
    unsigned* __restrict__ bar0, float* __restrict__ pred)
{
    const int tid = threadIdx.x;
    const int wv = tid >> 6, lane = tid & 63;
    const int blk = blockIdx.x;
    const int bg = blk & 1, rb = blk >> 1;
    const int bl = tid & 31, u = tid >> 5;
    const int mtl = bl >> 4, m16 = bl & 15;
    unsigned* cnt = bar0 + (bg << 11);      // one counter per domain, 8KB apart

    __shared__ float red1[16 * 272];        // 17KB (P2 then P3)
    __shared__ float red2[16 * 272];        // 17KB (P1, crosses barrier B)
    __shared__ float h2x[32 * 9];
    __shared__ ull hstage[32][2];

    for (int i = tid; i < 32 * 9; i += 256) h2x[i] = 0.f;

    // ---- resident weights (Wr2 streamed per step instead) ----
    short8 Wr0[2][8], Wr1h0[2][8], Wr1h1[2][8];
    {
        const short8* p0 = (const short8*)Wp0;
        const short8* p1 = (const short8*)Wp1;
        #pragma unroll
        for (int ot = 0; ot < 2; ++ot)
            #pragma unroll
            for (int kk = 0; kk < 8; ++kk) {
                Wr0[ot][kk]   = p0[((rb * 2 + ot) * KS0 + 8 * wv + kk) * 64 + lane];
                Wr1h0[ot][kk] = p1[((rb * 2 + ot) * KS1 + 8 * wv + kk) * 64 + lane];
                Wr1h1[ot][kk] = p1[((rb * 2 + ot) * KS1 + 32 + 8 * wv + kk) * 64 + lane];
            }
    }
    float wih0r[4][8], whh2r[4][8], b0r[4], b1r[4], b2r[4];
    #pragma unroll
    for (int g = 0; g < 4; ++g) {
        int row = rb * 8 + u + 1024 * g;
        #pragma unroll
        for (int d = 0; d < 8; ++d) wih0r[g][d] = wih0[row * 8 + d];
        b0r[g] = b0v[row];
        b1r[g] = b1v[row];
        int row2 = u + 8 * g;
        #pragma unroll
        for (int d = 0; d < 8; ++d) whh2r[g][d] = whh2[row2 * 8 + d];
        b2r[g] = b2v[row2];
    }
    float c0r = 0.f, c1r = 0.f, c2r = 0.f;
    unsigned ep = 0;

    auto redWrite = [&](float* red, f32x4 (&acc)[2][2]) {
        #pragma unroll
        for (int m = 0; m < 2; ++m)
            #pragma unroll
            for (int ot = 0; ot < 2; ++ot) {
                int base = ((wv * 2 + m) * 2 + ot) * 272 + (lane & 15) * 17 + (lane >> 4) * 4;
                #pragma unroll
                for (int r = 0; r < 4; ++r) red[base + r] = acc[m][ot][r];
            }
    };
    auto redSum = [&](const float* red, int g) {
        int rr = u * 4 + g, ot = rr >> 4, rr16 = rr & 15;
        float s = 0.f;
        #pragma unroll
        for (int w2i = 0; w2i < 4; ++w2i)
            s += red[((w2i * 2 + mtl) * 2 + ot) * 272 + rr16 * 17 + m16];
        return s;
    };
    auto hPublish = [&](unsigned short* Hw) {
        __syncthreads();
        if (tid < 32) {
            int b = bg * 32 + tid;
            int chunk = ((b >> 4) * KS0 + (rb >> 2)) * 64 + ((b & 15) | ((rb & 3) << 4));
            cstore16((unsigned short*)((ull*)Hw + chunk * 2),
                     hstage[tid][0], hstage[tid][1]);
        }
    };

    __syncthreads();

    // acc carries the P2 h1-half GEMM across the A barrier; h1(-1)=0 -> zero
    f32x4 acc[2][2];
    #pragma unroll
    for (int m = 0; m < 2; ++m)
        #pragma unroll
        for (int ot = 0; ot < 2; ++ot) acc[m][ot] = (f32x4){0.f, 0.f, 0.f, 0.f};

    // ---- preamble: P1(0) (h0(-1)=0 -> GEMM term vanishes) ----
    {
        float xv[8];
        int b = bg * 32 + bl;
        #pragma unroll
        for (int d = 0; d < 8; ++d) xv[d] = inp[(b * TT + 0) * DD + d];
        float g4[4];
        #pragma unroll
        for (int g = 0; g < 4; ++g) {
            float s = b0r[g];
            #pragma unroll
            for (int d = 0; d < 8; ++d) s += wih0r[g][d] * xv[d];
            g4[g] = s;
        }
        c0r = sigm(g4[0]) * ftanh(g4[2]);
        float hn = sigm(g4[3]) * ftanh(c0r);
        ((unsigned short*)hstage)[bl * 8 + u] = f2bf(hn);
        hPublish(H0a);                               // h0(0)
    }
    gbar_arrive(cnt, ++ep);

    for (int t = 0; t < NSTEP; ++t) {
        const int par = t & 1;
        const unsigned short* H0cur = par ? H0b : H0a;   // h0(t)
        unsigned short* H1w = par ? H1b : H1a;           // h1(t) dest
        unsigned short* H0nxt = par ? H0a : H0b;         // h0(t+1) dest
        const bool last = (t == NSTEP - 1);

        gbar_wait(cnt, ep);                  // wait A: h0(t) visible

        // ================= window A =================
        short8 pa[8], pb[8];
        {
            #pragma unroll
            for (int kk = 0; kk < 8; ++kk) {
                pa[kk] = cload16(H0cur + (((bg * 2 + 0) * KS0 + 8 * wv + kk) * 64 + lane) * 8);
                pb[kk] = cload16(H0cur + (((bg * 2 + 1) * KS0 + 8 * wv + kk) * 64 + lane) * 8);
            }
            kwait();
            #pragma unroll
            for (int kk = 0; kk < 8; ++kk) {
                #pragma unroll
                for (int ot = 0; ot < 2; ++ot) {
                    acc[0][ot] = __builtin_amdgcn_mfma_f32_16x16x32_bf16(pa[kk], Wr1h0[ot][kk], acc[0][ot], 0, 0, 0);
                    acc[1][ot] = __builtin_amdgcn_mfma_f32_16x16x32_bf16(pb[kk], Wr1h0[ot][kk], acc[1][ot], 0, 0, 0);
                }
            }
            redWrite(red1, acc);
            __syncthreads();
            float g4[4];
            #pragma unroll
            for (int g = 0; g < 4; ++g) g4[g] = b1r[g] + redSum(red1, g);
            c1r = sigm(g4[1]) * c1r + sigm(g4[0]) * ftanh(g4[2]);
            float hn = sigm(g4[3]) * ftanh(c1r);
            ((unsigned short*)hstage)[bl * 8 + u] = f2bf(hn);
            hPublish(H1w);                               // h1(t)
        }

        // ---- gap B BEFORE arrive B: h1 store-acks drain under this GEMM ----
        if (!last) {
            f32x4 a1[2][2];
            #pragma unroll
            for (int m = 0; m < 2; ++m)
                #pragma unroll
                for (int ot = 0; ot < 2; ++ot) a1[m][ot] = (f32x4){0.f, 0.f, 0.f, 0.f};
            #pragma unroll
            for (int kk = 0; kk < 8; ++kk) {
                #pragma unroll
                for (int ot = 0; ot < 2; ++ot) {
                    a1[0][ot] = __builtin_amdgcn_mfma_f32_16x16x32_bf16(pa[kk], Wr0[ot][kk], a1[0][ot], 0, 0, 0);
                    a1[1][ot] = __builtin_amdgcn_mfma_f32_16x16x32_bf16(pb[kk], Wr0[ot][kk], a1[1][ot], 0, 0, 0);
                }
            }
            redWrite(red2, a1);
        }
        gbar_arrive(cnt, ++ep);              // arrive B
        gbar_wait(cnt, ep);                  // wait B: h1(t) visible

        // ================= window B =================
        {
            // stream Wr2 (L1/L2-cached, immutable) alongside the h1 loads
            const short8* p2w = (const short8*)Wp2;
            short8 w2[2][8];
            #pragma unroll
            for (int ot = 0; ot < 2; ++ot)
                #pragma unroll
                for (int kk = 0; kk < 8; ++kk)
                    w2[ot][kk] = p2w[(ot * KS0 + 8 * wv + kk) * 64 + lane];
            short8 qa[8], qb[8];
            #pragma unroll
            for (int kk = 0; kk < 8; ++kk) {
                qa[kk] = cload16(H1w + (((bg * 2 + 0) * KS0 + 8 * wv + kk) * 64 + lane) * 8);
                qb[kk] = cload16(H1w + (((bg * 2 + 1) * KS0 + 8 * wv + kk) * 64 + lane) * 8);
            }
            kwait();
            f32x4 a3[2][2];
            #pragma unroll
            for (int m = 0; m < 2; ++m)
                #pragma unroll
                for (int ot = 0; ot < 2; ++ot) a3[m][ot] = (f32x4){0.f, 0.f, 0.f, 0.f};
            #pragma unroll
            for (int kk = 0; kk < 8; ++kk) {
                #pragma unroll
                for (int ot = 0; ot < 2; ++ot) {
                    a3[0][ot] = __builtin_amdgcn_mfma_f32_16x16x32_bf16(qa[kk], w2[ot][kk], a3[0][ot], 0, 0, 0);
                    a3[1][ot] = __builtin_amdgcn_mfma_f32_16x16x32_bf16(qb[kk], w2[ot][kk], a3[1][ot], 0, 0, 0);
                }
            }
            redWrite(red1, a3);             // red1 free since window A's redSum
            __syncthreads();
            // P3 cell
            float xo[8];
            #pragma unroll
            for (int d = 0; d < 8; ++d) xo[d] = h2x[bl * 9 + d];
            float g4[4];
            #pragma unroll
            for (int g = 0; g < 4; ++g) {
                float s = b2r[g] + redSum(red1, g);
                #pragma unroll
                for (int d = 0; d < 8; ++d) s += whh2r[g][d] * xo[d];
                g4[g] = s;
            }
            float cn = sigm(g4[1]) * c2r + sigm(g4[0]) * ftanh(g4[2]);
            c2r = cn;
            float hn2 = sigm(g4[3]) * ftanh(cn);
            __syncthreads();                // old-h2x reads done
            h2x[bl * 9 + u] = hn2;
            if (rb == 0 && t >= ENC - 1)
                pred[((bg * 32 + bl) * HOR + (t - (ENC - 1))) * DD + u] = hn2;

            if (!last) {
                __syncthreads();            // h2x(t) visible
                const int tt = t + 1;
                float xv[8];
                if (tt < ENC) {
                    int b = bg * 32 + bl;
                    #pragma unroll
                    for (int d = 0; d < 8; ++d) xv[d] = inp[(b * TT + tt) * DD + d];
                } else {
                    #pragma unroll
                    for (int d = 0; d < 8; ++d) xv[d] = h2x[bl * 9 + d];
                }
                float g1[4];
                #pragma unroll
                for (int g = 0; g < 4; ++g) {
                    float s = b0r[g] + redSum(red2, g);
                    #pragma unroll
                    for (int d = 0; d < 8; ++d) s += wih0r[g][d] * xv[d];
                    g1[g] = s;
                }
                c0r = sigm(g1[1]) * c0r + sigm(g1[0]) * ftanh(g1[2]);
                float hn0 = sigm(g1[3]) * ftanh(c0r);
                ((unsigned short*)hstage)[bl * 8 + u] = f2bf(hn0);
                hPublish(H0nxt);                          // h0(t+1)

                // ---- gap A for t+1 BEFORE arrive A: h0 store-acks drain
                // under this GEMM; result carried in acc across the barrier.
                #pragma unroll
                for (int m = 0; m < 2; ++m)
                    #pragma unroll
                    for (int ot = 0; ot < 2; ++ot) acc[m][ot] = (f32x4){0.f, 0.f, 0.f, 0.f};
                #pragma unroll
                for (int kk = 0; kk < 8; ++kk) {
                    #pragma unroll
                    for (int ot = 0; ot < 2; ++ot) {
                        acc[0][ot] = __builtin_amdgcn_mfma_f32_16x16x32_bf16(qa[kk], Wr1h1[ot][kk], acc[0][ot], 0, 0, 0);
                        acc[1][ot] = __builtin_amdgcn_mfma_f32_16x16x32_bf16(qb[kk], Wr1h1[ot][kk], acc[1][ot], 0, 0, 0);
                    }
                }
                gbar_arrive(cnt, ++ep);               // arrive A
            }
        }
    }
}

// ---------------- host ----------------

extern "C" void kernel_launch(void* const* d_in, const int* in_sizes, int n_in,
                              void* d_out, int out_size, void* d_ws, size_t ws_size,
                              hipStream_t stream)
{
    const float* inp  = (const float*)d_in[0];
    const float* wih0 = (const float*)d_in[1];
    const float* whh0 = (const float*)d_in[2];
    const float* b0v  = (const float*)d_in[3];
    const float* wih1 = (const float*)d_in[4];
    const float* whh1 = (const float*)d_in[5];
    const float* b1v  = (const float*)d_in[6];
    const float* wih2 = (const float*)d_in[7];
    const float* whh2 = (const float*)d_in[8];
    const float* b2v  = (const float*)d_in[9];
    float* out = (float*)d_out;   // pred[172032] | y[172032] | loss[8]

    char* base = (char*)d_ws;
    size_t off = 0;
    auto carve = [&](size_t bytes) -> void* {
        void* p = base + off;
        off += (bytes + 255) & ~((size_t)255);
        return p;
    };
    unsigned short* Wp0 = (unsigned short*)carve((size_t)128 * 2 * KS0 * 64 * 8 * 2);
    unsigned short* Wp1 = (unsigned short*)carve((size_t)128 * 2 * KS1 * 64 * 8 * 2);
    unsigned short* Wp2 = (unsigned short*)carve((size_t)2 * KS0 * 64 * 8 * 2);
    size_t state_off = off;
    unsigned short* H0a = (unsigned short*)carve(B64 * H * 2);
    unsigned short* H0b = (unsigned short*)carve(B64 * H * 2);
    unsigned short* H1a = (unsigned short*)carve(B64 * H * 2);
    unsigned short* H1b = (unsigned short*)carve(B64 * H * 2);
    unsigned* bar = (unsigned*)carve(2 * 8192 * 4);   // 2 domains (counters 8KB apart)
    size_t state_bytes = off - state_off;
    if (off > ws_size) return;

    zero_k<<<64, 256, 0, stream>>>((unsigned int*)(base + state_off), (int)(state_bytes / 4));
    pack0_k<<<2048, 256, 0, stream>>>(whh0, Wp0);
    pack1_k<<<4096, 256, 0, stream>>>(wih1, whh1, Wp1);
    pack2_k<<<32, 256, 0, stream>>>(wih2, Wp2);
    copy_y_k<<<672, 256, 0, stream>>>(inp, out + 172032);

    persist_k<<<NBLK, 256, 0, stream>>>(Wp0, Wp1, Wp2, wih0, b0v, b1v, whh2, b2v,
                                        inp, H0a, H0b, H1a, H1b, bar, out);

    loss_k<<<1, 256, 0, stream>>>(out, out + 172032, out + 344064);
}

// Round 9
// 3991.106 us; speedup vs baseline: 1.0552x; 1.0552x over previous
//
#include <hip/hip_runtime.h>
#include <math.h>

#define B64 64
#define H 1024
#define DD 8
#define ENC 96
#define HOR 336
#define TT 432
#define NSTEP 431
#define NBLK 256
#define KS0 32      // K=1024 in 32-wide chunks
#define KS1 64      // K=2048

typedef __attribute__((ext_vector_type(8))) short short8;
typedef __attribute__((ext_vector_type(4))) float f32x4;
typedef __attribute__((ext_vector_type(4))) unsigned int u32x4;
typedef unsigned long long ull;

__device__ __forceinline__ unsigned short f2bf(float x) {
    union { float f; unsigned u; } v; v.f = x;
    unsigned r = v.u + 0x7fffu + ((v.u >> 16) & 1u);
    return (unsigned short)(r >> 16);
}
__device__ __forceinline__ float sigm(float x) {
    return __builtin_amdgcn_rcpf(1.0f + __expf(-x));
}
__device__ __forceinline__ float ftanh(float x) {
    float e = __expf(fminf(x, 10.0f) * 2.0f);   // clamp: avoid inf/inf
    return (e - 1.0f) * __builtin_amdgcn_rcpf(e + 1.0f);
}

// Agent-coherent 16B load/store via one dwordx4 (sc0 sc1) — halves coherent
// transaction count vs 2x8B atomics. Callers MUST kwait() before using loads.
__device__ __forceinline__ short8 cload16(const unsigned short* p) {
    u32x4 v;
    asm volatile("global_load_dwordx4 %0, %1, off sc0 sc1"
                 : "=v"(v) : "v"(p) : "memory");
    union { u32x4 u; short8 s; } c; c.u = v; return c.s;
}
__device__ __forceinline__ void cstore16(unsigned short* p, ull lo, ull hi) {
    union { ull u[2]; u32x4 v; } c; c.u[0] = lo; c.u[1] = hi;
    asm volatile("global_store_dwordx4 %0, %1, off sc0 sc1"
                 :: "v"(p), "v"(c.v) : "memory");
}
__device__ __forceinline__ void kwait() {
    asm volatile("s_waitcnt vmcnt(0)" ::: "memory");
    __builtin_amdgcn_sched_barrier(0);      // guide rule 18: pin uses after wait
}

// ---------------- prep kernels (verified) ----------------

__global__ void zero_k(unsigned int* __restrict__ p, int n) {
    for (int i = blockIdx.x * 256 + threadIdx.x; i < n; i += gridDim.x * 256) p[i] = 0u;
}

__global__ void pack0_k(const float* __restrict__ w, unsigned short* __restrict__ dst) {
    const int total = 128 * 2 * KS0 * 64 * 8;
    for (int idx = blockIdx.x * 256 + threadIdx.x; idx < total; idx += gridDim.x * 256) {
        int j = idx & 7, lane = (idx >> 3) & 63, ks = (idx >> 9) & 31, nt = (idx >> 14) & 1, nb = idx >> 15;
        int rr = nt * 16 + (lane & 15);
        int row = nb * 8 + (rr >> 2) + 1024 * (rr & 3);
        int k = ks * 32 + ((lane >> 4) << 3) + j;
        dst[idx] = f2bf(w[row * 1024 + k]);
    }
}

__global__ void pack1_k(const float* __restrict__ wih, const float* __restrict__ whh,
                        unsigned short* __restrict__ dst) {
    const int total = 128 * 2 * KS1 * 64 * 8;
    for (int idx = blockIdx.x * 256 + threadIdx.x; idx < total; idx += gridDim.x * 256) {
        int j = idx & 7, lane = (idx >> 3) & 63, ks = (idx >> 9) & 63, nt = (idx >> 15) & 1, nb = idx >> 16;
        int rr = nt * 16 + (lane & 15);
        int row = nb * 8 + (rr >> 2) + 1024 * (rr & 3);
        int k = ks * 32 + ((lane >> 4) << 3) + j;
        float v = (k < 1024) ? wih[row * 1024 + k] : whh[row * 1024 + (k - 1024)];
        dst[idx] = f2bf(v);
    }
}

__global__ void pack2_k(const float* __restrict__ w, unsigned short* __restrict__ dst) {
    const int total = 2 * KS0 * 64 * 8;
    for (int idx = blockIdx.x * 256 + threadIdx.x; idx < total; idx += gridDim.x * 256) {
        int j = idx & 7, lane = (idx >> 3) & 63, ks = (idx >> 9) & 31, nt = (idx >> 14) & 1;
        int rr = nt * 16 + (lane & 15);
        int row = (rr >> 2) + 8 * (rr & 3);
        int k = ks * 32 + ((lane >> 4) << 3) + j;
        dst[idx] = f2bf(w[row * 1024 + k]);
    }
}

__global__ void copy_y_k(const float* __restrict__ inp, float* __restrict__ y) {
    const int total = B64 * HOR * DD;
    for (int i = blockIdx.x * 256 + threadIdx.x; i < total; i += gridDim.x * 256) {
        int b = i / (HOR * DD);
        int rem = i - b * (HOR * DD);
        y[i] = inp[b * (TT * DD) + ENC * DD + rem];
    }
}

__global__ void loss_k(const float* __restrict__ pred, const float* __restrict__ y,
                       float* __restrict__ loss) {
    __shared__ float part[256];
    int tid = threadIdx.x;
    int dd = tid & 7, cc = tid >> 3;
    float s = 0.f;
    for (int i = cc; i < B64 * HOR; i += 32) {
        float d = pred[i * 8 + dd] - y[i * 8 + dd];
        s += d * d;
    }
    part[tid] = s;
    __syncthreads();
    if (tid < 8) {
        float t = 0.f;
        for (int r = 0; r < 32; ++r) t += part[r * 8 + tid];
        loss[tid] = t / (float)(B64 * HOR);
    }
}

// ---- hybrid counting barrier: 16 MALL-resident atomic counters/domain ----
// R7 proved atomics keep flag lines MALL-owned (FETCH -62MB: no per-poll HBM
// refetch) but 128 RMWs on ONE line serialize (~1800cy/round, +0.75us). R6's
// 128-line flag sweep avoided serialization but re-fetched 128 lines from HBM
// per poll. Hybrid: block rb adds to counter[rb&15] (8 RMWs/line ≈ 110cy,
// overlapped); wait polls 16 hot MALL lines in parallel (lanes 0..15).
// Safety: monotone counting barrier; arrive(ep) is program-ordered after
// wait(ep-1), so counter[i]==8*ep first occurs when its 8 blocks arrived ep
// times (induction; no early-arrive fast path in this schedule).
__device__ __forceinline__ void gbar_arrive(unsigned* ctr, int rb, unsigned) {
    if (threadIdx.x == 0) {
        __builtin_amdgcn_s_waitcnt(0x0f70);     // vmcnt(0): publish drained
        atomicAdd(ctr + (rb & 15) * 32, 1u);    // counters 128B apart
    }
}
__device__ __forceinline__ void gbar_wait(unsigned* ctr, unsigned ep) {
    const int tid = threadIdx.x;
    if (tid < 16) {
        const unsigned tgt = ep * 8u;
        const unsigned* f = ctr + tid * 32;
        for (;;) {
            unsigned a = __hip_atomic_load(f, __ATOMIC_RELAXED,
                                           __HIP_MEMORY_SCOPE_AGENT);
            if (__all(a >= tgt)) break;
        }
    }
    __syncthreads();
}

// ---------------- persistent recurrence kernel ----------------
// Drain-overlapped schedule (per step, 2 barriers):
//  wait A   -> h0(t) visible
//  window A: load pa/pb = h0(t) (16B sc-loads); acc += MFMA(pa/pb, Wr1h0)
//            [acc carries the h1(t-1) half from the previous window-B tail];
//            reduce; P2 cell -> publish h1(t);
//            P1(t+1) GEMM on pa/pb -> red2   [h1 store-acks drain under this]
//            arrive B
//  wait B   -> h1(t) visible
//  window B: load qa/qb = h1(t); P3 GEMM (streamed Wr2) -> reduce; P3 cell ->
//            h2x/pred; P1 cell (red2 + wih0*x) -> publish h0(t+1);
//            acc = MFMA(qa/qb, Wr1h1)        [h0 store-acks drain under this]
//            arrive A
__global__ __launch_bounds__(256, 1) void persist_k(
    const unsigned short* __restrict__ Wp0,
    const unsigned short* __restrict__ Wp1,
    const unsigned short* __restrict__ Wp2,
    const float* __restrict__ wih0, const float* __restrict__ b0v,
    const float* __restrict__ b1v,
    const float* __restrict__ whh2, const float* __restrict__ b2v,
    const float* __restrict__ inp,
    unsigned short* __restrict__ H0a, unsigned short* __restrict__ H0b,
    unsigned short* __restrict__ H1a, unsigned short* __restrict__ H1b,
    unsigned* __restrict__ bar0, float* __restrict__ pred)
{
    const int tid = threadIdx.x;
    const int wv = tid >> 6, lane = tid & 63;
    const int blk = blockIdx.x;
    const int bg = blk & 1, rb = blk >> 1;
    const int bl = tid & 31, u = tid >> 5;
    const int mtl = bl >> 4, m16 = bl & 15;
    unsigned* ctr = bar0 + (bg << 11);      // 16 counters/domain, 8KB apart

    __shared__ float red1[16 * 272];        // 17KB (P2 then P3)
    __shared__ float red2[16 * 272];        // 17KB (P1, crosses barrier B)
    __shared__ float h2x[32 * 9];
    __shared__ ull hstage[32][2];

    for (int i = tid; i < 32 * 9; i += 256) h2x[i] = 0.f;

    // ---- resident weights (Wr2 streamed per step instead) ----
    short8 Wr0[2][8], Wr1h0[2][8], Wr1h1[2][8];
    {
        const short8* p0 = (const short8*)Wp0;
        const short8* p1 = (const short8*)Wp1;
        #pragma unroll
        for (int ot = 0; ot < 2; ++ot)
            #pragma unroll
            for (int kk = 0; kk < 8; ++kk) {
                Wr0[ot][kk]   = p0[((rb * 2 + ot) * KS0 + 8 * wv + kk) * 64 + lane];
                Wr1h0[ot][kk] = p1[((rb * 2 + ot) * KS1 + 8 * wv + kk) * 64 + lane];
                Wr1h1[ot][kk] = p1[((rb * 2 + ot) * KS1 + 32 + 8 * wv + kk) * 64 + lane];
            }
    }
    float wih0r[4][8], whh2r[4][8], b0r[4], b1r[4], b2r[4];
    #pragma unroll
    for (int g = 0; g < 4; ++g) {
        int row = rb * 8 + u + 1024 * g;
        #pragma unroll
        for (int d = 0; d < 8; ++d) wih0r[g][d] = wih0[row * 8 + d];
        b0r[g] = b0v[row];
        b1r[g] = b1v[row];
        int row2 = u + 8 * g;
        #pragma unroll
        for (int d = 0; d < 8; ++d) whh2r[g][d] = whh2[row2 * 8 + d];
        b2r[g] = b2v[row2];
    }
    float c0r = 0.f, c1r = 0.f, c2r = 0.f;
    unsigned ep = 0;

    auto redWrite = [&](float* red, f32x4 (&acc)[2][2]) {
        #pragma unroll
        for (int m = 0; m < 2; ++m)
            #pragma unroll
            for (int ot = 0; ot < 2; ++ot) {
                int base = ((wv * 2 + m) * 2 + ot) * 272 + (lane & 15) * 17 + (lane >> 4) * 4;
                #pragma unroll
                for (int r = 0; r < 4; ++r) red[base + r] = acc[m][ot][r];
            }
    };
    auto redSum = [&](const float* red, int g) {
        int rr = u * 4 + g, ot = rr >> 4, rr16 = rr & 15;
        float s = 0.f;
        #pragma unroll
        for (int w2i = 0; w2i < 4; ++w2i)
            s += red[((w2i * 2 + mtl) * 2 + ot) * 272 + rr16 * 17 + m16];
        return s;
    };
    auto hPublish = [&](unsigned short* Hw) {
        __syncthreads();
        if (tid < 32) {
            int b = bg * 32 + tid;
            int chunk = ((b >> 4) * KS0 + (rb >> 2)) * 64 + ((b & 15) | ((rb & 3) << 4));
            cstore16((unsigned short*)((ull*)Hw + chunk * 2),
                     hstage[tid][0], hstage[tid][1]);
        }
    };

    __syncthreads();

    // acc carries the P2 h1-half GEMM across the A barrier; h1(-1)=0 -> zero
    f32x4 acc[2][2];
    #pragma unroll
    for (int m = 0; m < 2; ++m)
        #pragma unroll
        for (int ot = 0; ot < 2; ++ot) acc[m][ot] = (f32x4){0.f, 0.f, 0.f, 0.f};

    // ---- preamble: P1(0) (h0(-1)=0 -> GEMM term vanishes) ----
    {
        float xv[8];
        int b = bg * 32 + bl;
        #pragma unroll
        for (int d = 0; d < 8; ++d) xv[d] = inp[(b * TT + 0) * DD + d];
        float g4[4];
        #pragma unroll
        for (int g = 0; g < 4; ++g) {
            float s = b0r[g];
            #pragma unroll
            for (int d = 0; d < 8; ++d) s += wih0r[g][d] * xv[d];
            g4[g] = s;
        }
        c0r = sigm(g4[0]) * ftanh(g4[2]);
        float hn = sigm(g4[3]) * ftanh(c0r);
        ((unsigned short*)hstage)[bl * 8 + u] = f2bf(hn);
        hPublish(H0a);                               // h0(0)
    }
    gbar_arrive(ctr, rb, ++ep);

    for (int t = 0; t < NSTEP; ++t) {
        const int par = t & 1;
        const unsigned short* H0cur = par ? H0b : H0a;   // h0(t)
        unsigned short* H1w = par ? H1b : H1a;           // h1(t) dest
        unsigned short* H0nxt = par ? H0a : H0b;         // h0(t+1) dest
        const bool last = (t == NSTEP - 1);

        gbar_wait(ctr, ep);                  // wait A: h0(t) visible

        // ================= window A =================
        short8 pa[8], pb[8];
        {
            #pragma unroll
            for (int kk = 0; kk < 8; ++kk) {
                pa[kk] = cload16(H0cur + (((bg * 2 + 0) * KS0 + 8 * wv + kk) * 64 + lane) * 8);
                pb[kk] = cload16(H0cur + (((bg * 2 + 1) * KS0 + 8 * wv + kk) * 64 + lane) * 8);
            }
            kwait();
            #pragma unroll
            for (int kk = 0; kk < 8; ++kk) {
                #pragma unroll
                for (int ot = 0; ot < 2; ++ot) {
                    acc[0][ot] = __builtin_amdgcn_mfma_f32_16x16x32_bf16(pa[kk], Wr1h0[ot][kk], acc[0][ot], 0, 0, 0);
                    acc[1][ot] = __builtin_amdgcn_mfma_f32_16x16x32_bf16(pb[kk], Wr1h0[ot][kk], acc[1][ot], 0, 0, 0);
                }
            }
            redWrite(red1, acc);
            __syncthreads();
            float g4[4];
            #pragma unroll
            for (int g = 0; g < 4; ++g) g4[g] = b1r[g] + redSum(red1, g);
            c1r = sigm(g4[1]) * c1r + sigm(g4[0]) * ftanh(g4[2]);
            float hn = sigm(g4[3]) * ftanh(c1r);
            ((unsigned short*)hstage)[bl * 8 + u] = f2bf(hn);
            hPublish(H1w);                               // h1(t)
        }

        // ---- gap B BEFORE arrive B: h1 store-acks drain under this GEMM ----
        if (!last) {
            f32x4 a1[2][2];
            #pragma unroll
            for (int m = 0; m < 2; ++m)
                #pragma unroll
                for (int ot = 0; ot < 2; ++ot) a1[m][ot] = (f32x4){0.f, 0.f, 0.f, 0.f};
            #pragma unroll
            for (int kk = 0; kk < 8; ++kk) {
                #pragma unroll
                for (int ot = 0; ot < 2; ++ot) {
                    a1[0][ot] = __builtin_amdgcn_mfma_f32_16x16x32_bf16(pa[kk], Wr0[ot][kk], a1[0][ot], 0, 0, 0);
                    a1[1][ot] = __builtin_amdgcn_mfma_f32_16x16x32_bf16(pb[kk], Wr0[ot][kk], a1[1][ot], 0, 0, 0);
                }
            }
            redWrite(red2, a1);
        }
        gbar_arrive(ctr, rb, ++ep);          // arrive B
        gbar_wait(ctr, ep);                  // wait B: h1(t) visible

        // ================= window B =================
        {
            // stream Wr2 (L1/L2-cached, immutable) alongside the h1 loads
            const short8* p2w = (const short8*)Wp2;
            short8 w2[2][8];
            #pragma unroll
            for (int ot = 0; ot < 2; ++ot)
                #pragma unroll
                for (int kk = 0; kk < 8; ++kk)
                    w2[ot][kk] = p2w[(ot * KS0 + 8 * wv + kk) * 64 + lane];
            short8 qa[8], qb[8];
            #pragma unroll
            for (int kk = 0; kk < 8; ++kk) {
                qa[kk] = cload16(H1w + (((bg * 2 + 0) * KS0 + 8 * wv + kk) * 64 + lane) * 8);
                qb[kk] = cload16(H1w + (((bg * 2 + 1) * KS0 + 8 * wv + kk) * 64 + lane) * 8);
            }
            kwait();
            f32x4 a3[2][2];
            #pragma unroll
            for (int m = 0; m < 2; ++m)
                #pragma unroll
                for (int ot = 0; ot < 2; ++ot) a3[m][ot] = (f32x4){0.f, 0.f, 0.f, 0.f};
            #pragma unroll
            for (int kk = 0; kk < 8; ++kk) {
                #pragma unroll
                for (int ot = 0; ot < 2; ++ot) {
                    a3[0][ot] = __builtin_amdgcn_mfma_f32_16x16x32_bf16(qa[kk], w2[ot][kk], a3[0][ot], 0, 0, 0);
                    a3[1][ot] = __builtin_amdgcn_mfma_f32_16x16x32_bf16(qb[kk], w2[ot][kk], a3[1][ot], 0, 0, 0);
                }
            }
            redWrite(red1, a3);             // red1 free since window A's redSum
            __syncthreads();
            // P3 cell
            float xo[8];
            #pragma unroll
            for (int d = 0; d < 8; ++d) xo[d] = h2x[bl * 9 + d];
            float g4[4];
            #pragma unroll
            for (int g = 0; g < 4; ++g) {
                float s = b2r[g] + redSum(red1, g);
                #pragma unroll
                for (int d = 0; d < 8; ++d) s += whh2r[g][d] * xo[d];
                g4[g] = s;
            }
            float cn = sigm(g4[1]) * c2r + sigm(g4[0]) * ftanh(g4[2]);
            c2r = cn;
            float hn2 = sigm(g4[3]) * ftanh(cn);
            __syncthreads();                // old-h2x reads done
            h2x[bl * 9 + u] = hn2;
            if (rb == 0 && t >= ENC - 1)
                pred[((bg * 32 + bl) * HOR + (t - (ENC - 1))) * DD + u] = hn2;

            if (!last) {
                __syncthreads();            // h2x(t) visible
                const int tt = t + 1;
                float xv[8];
                if (tt < ENC) {
                    int b = bg * 32 + bl;
                    #pragma unroll
                    for (int d = 0; d < 8; ++d) xv[d] = inp[(b * TT + tt) * DD + d];
                } else {
                    #pragma unroll
                    for (int d = 0; d < 8; ++d) xv[d] = h2x[bl * 9 + d];
                }
                float g1[4];
                #pragma unroll
                for (int g = 0; g < 4; ++g) {
                    float s = b0r[g] + redSum(red2, g);
                    #pragma unroll
                    for (int d = 0; d < 8; ++d) s += wih0r[g][d] * xv[d];
                    g1[g] = s;
                }
                c0r = sigm(g1[1]) * c0r + sigm(g1[0]) * ftanh(g1[2]);
                float hn0 = sigm(g1[3]) * ftanh(c0r);
                ((unsigned short*)hstage)[bl * 8 + u] = f2bf(hn0);
                hPublish(H0nxt);                          // h0(t+1)

                // ---- gap A for t+1 BEFORE arrive A: h0 store-acks drain
                // under this GEMM; result carried in acc across the barrier.
                #pragma unroll
                for (int m = 0; m < 2; ++m)
                    #pragma unroll
                    for (int ot = 0; ot < 2; ++ot) acc[m][ot] = (f32x4){0.f, 0.f, 0.f, 0.f};
                #pragma unroll
                for (int kk = 0; kk < 8; ++kk) {
                    #pragma unroll
                    for (int ot = 0; ot < 2; ++ot) {
                        acc[0][ot] = __builtin_amdgcn_mfma_f32_16x16x32_bf16(qa[kk], Wr1h1[ot][kk], acc[0][ot], 0, 0, 0);
                        acc[1][ot] = __builtin_amdgcn_mfma_f32_16x16x32_bf16(qb[kk], Wr1h1[ot][kk], acc[1][ot], 0, 0, 0);
                    }
                }
                gbar_arrive(ctr, rb, ++ep);               // arrive A
            }
        }
    }
}

// ---------------- host ----------------

extern "C" void kernel_launch(void* const* d_in, const int* in_sizes, int n_in,
                              void* d_out, int out_size, void* d_ws, size_t ws_size,
                              hipStream_t stream)
{
    const float* inp  = (const float*)d_in[0];
    const float* wih0 = (const float*)d_in[1];
    const float* whh0 = (const float*)d_in[2];
    const float* b0v  = (const float*)d_in[3];
    const float* wih1 = (const float*)d_in[4];
    const float* whh1 = (const float*)d_in[5];
    const float* b1v  = (const float*)d_in[6];
    const float* wih2 = (const float*)d_in[7];
    const float* whh2 = (const float*)d_in[8];
    const float* b2v  = (const float*)d_in[9];
    float* out = (float*)d_out;   // pred[172032] | y[172032] | loss[8]

    char* base = (char*)d_ws;
    size_t off = 0;
    auto carve = [&](size_t bytes) -> void* {
        void* p = base + off;
        off += (bytes + 255) & ~((size_t)255);
        return p;
    };
    unsigned short* Wp0 = (unsigned short*)carve((size_t)128 * 2 * KS0 * 64 * 8 * 2);
    unsigned short* Wp1 = (unsigned short*)carve((size_t)128 * 2 * KS1 * 64 * 8 * 2);
    unsigned short* Wp2 = (unsigned short*)carve((size_t)2 * KS0 * 64 * 8 * 2);
    size_t state_off = off;
    unsigned short* H0a = (unsigned short*)carve(B64 * H * 2);
    unsigned short* H0b = (unsigned short*)carve(B64 * H * 2);
    unsigned short* H1a = (unsigned short*)carve(B64 * H * 2);
    unsigned short* H1b = (unsigned short*)carve(B64 * H * 2);
    unsigned* bar = (unsigned*)carve(2 * 8192 * 4);   // 2 domains x 16 counters
    size_t state_bytes = off - state_off;
    if (off > ws_size) return;

    zero_k<<<64, 256, 0, stream>>>((unsigned int*)(base + state_off), (int)(state_bytes / 4));
    pack0_k<<<2048, 256, 0, stream>>>(whh0, Wp0);
    pack1_k<<<4096, 256, 0, stream>>>(wih1, whh1, Wp1);
    pack2_k<<<32, 256, 0, stream>>>(wih2, Wp2);
    copy_y_k<<<672, 256, 0, stream>>>(inp, out + 172032);

    persist_k<<<NBLK, 256, 0, stream>>>(Wp0, Wp1, Wp2, wih0, b0v, b1v, whh2, b2v,
                                        inp, H0a, H0b, H1a, H1b, bar, out);

    loss_k<<<1, 256, 0, stream>>>(out, out + 172032, out + 344064);
}

// Round 10
// 3483.463 us; speedup vs baseline: 1.2090x; 1.1457x over previous
//
#include <hip/hip_runtime.h>
#include <math.h>

#define B64 64
#define H 1024
#define DD 8
#define ENC 96
#define HOR 336
#define TT 432
#define NSTEP 431
#define NBLK 256
#define KS0 32      // K=1024 in 32-wide chunks
#define KS1 64      // K=2048
#define RSEG 392    // red segment stride (words): 392%32=8 -> mtl groups +16 banks
#define RCOL 24     // red column stride (words): 4*24%32=0 -> u groups +0 (2-way, free)

typedef __attribute__((ext_vector_type(8))) short short8;
typedef __attribute__((ext_vector_type(4))) float f32x4;
typedef __attribute__((ext_vector_type(4))) unsigned int u32x4;
typedef unsigned long long ull;

__device__ __forceinline__ unsigned short f2bf(float x) {
    union { float f; unsigned u; } v; v.f = x;
    unsigned r = v.u + 0x7fffu + ((v.u >> 16) & 1u);
    return (unsigned short)(r >> 16);
}
__device__ __forceinline__ float sigm(float x) {
    return __builtin_amdgcn_rcpf(1.0f + __expf(-x));
}
__device__ __forceinline__ float ftanh(float x) {
    float e = __expf(fminf(x, 10.0f) * 2.0f);   // clamp: avoid inf/inf
    return (e - 1.0f) * __builtin_amdgcn_rcpf(e + 1.0f);
}

// Agent-coherent 16B load/store via one dwordx4 (sc0 sc1) — halves coherent
// transaction count vs 2x8B atomics. Callers MUST kwait() before using loads.
__device__ __forceinline__ short8 cload16(const unsigned short* p) {
    u32x4 v;
    asm volatile("global_load_dwordx4 %0, %1, off sc0 sc1"
                 : "=v"(v) : "v"(p) : "memory");
    union { u32x4 u; short8 s; } c; c.u = v; return c.s;
}
__device__ __forceinline__ void cstore16(unsigned short* p, ull lo, ull hi) {
    union { ull u[2]; u32x4 v; } c; c.u[0] = lo; c.u[1] = hi;
    asm volatile("global_store_dwordx4 %0, %1, off sc0 sc1"
                 :: "v"(p), "v"(c.v) : "memory");
}
__device__ __forceinline__ void kwait() {
    asm volatile("s_waitcnt vmcnt(0)" ::: "memory");
    __builtin_amdgcn_sched_barrier(0);      // guide rule 18: pin uses after wait
}

// ---------------- prep kernels (verified) ----------------

__global__ void zero_k(unsigned int* __restrict__ p, int n) {
    for (int i = blockIdx.x * 256 + threadIdx.x; i < n; i += gridDim.x * 256) p[i] = 0u;
}

__global__ void pack0_k(const float* __restrict__ w, unsigned short* __restrict__ dst) {
    const int total = 128 * 2 * KS0 * 64 * 8;
    for (int idx = blockIdx.x * 256 + threadIdx.x; idx < total; idx += gridDim.x * 256) {
        int j = idx & 7, lane = (idx >> 3) & 63, ks = (idx >> 9) & 31, nt = (idx >> 14) & 1, nb = idx >> 15;
        int rr = nt * 16 + (lane & 15);
        int row = nb * 8 + (rr >> 2) + 1024 * (rr & 3);
        int k = ks * 32 + ((lane >> 4) << 3) + j;
        dst[idx] = f2bf(w[row * 1024 + k]);
    }
}

__global__ void pack1_k(const float* __restrict__ wih, const float* __restrict__ whh,
                        unsigned short* __restrict__ dst) {
    const int total = 128 * 2 * KS1 * 64 * 8;
    for (int idx = blockIdx.x * 256 + threadIdx.x; idx < total; idx += gridDim.x * 256) {
        int j = idx & 7, lane = (idx >> 3) & 63, ks = (idx >> 9) & 63, nt = (idx >> 15) & 1, nb = idx >> 16;
        int rr = nt * 16 + (lane & 15);
        int row = nb * 8 + (rr >> 2) + 1024 * (rr & 3);
        int k = ks * 32 + ((lane >> 4) << 3) + j;
        float v = (k < 1024) ? wih[row * 1024 + k] : whh[row * 1024 + (k - 1024)];
        dst[idx] = f2bf(v);
    }
}

__global__ void pack2_k(const float* __restrict__ w, unsigned short* __restrict__ dst) {
    const int total = 2 * KS0 * 64 * 8;
    for (int idx = blockIdx.x * 256 + threadIdx.x; idx < total; idx += gridDim.x * 256) {
        int j = idx & 7, lane = (idx >> 3) & 63, ks = (idx >> 9) & 31, nt = (idx >> 14) & 1;
        int rr = nt * 16 + (lane & 15);
        int row = (rr >> 2) + 8 * (rr & 3);
        int k = ks * 32 + ((lane >> 4) << 3) + j;
        dst[idx] = f2bf(w[row * 1024 + k]);
    }
}

__global__ void copy_y_k(const float* __restrict__ inp, float* __restrict__ y) {
    const int total = B64 * HOR * DD;
    for (int i = blockIdx.x * 256 + threadIdx.x; i < total; i += gridDim.x * 256) {
        int b = i / (HOR * DD);
        int rem = i - b * (HOR * DD);
        y[i] = inp[b * (TT * DD) + ENC * DD + rem];
    }
}

__global__ void loss_k(const float* __restrict__ pred, const float* __restrict__ y,
                       float* __restrict__ loss) {
    __shared__ float part[256];
    int tid = threadIdx.x;
    int dd = tid & 7, cc = tid >> 3;
    float s = 0.f;
    for (int i = cc; i < B64 * HOR; i += 32) {
        float d = pred[i * 8 + dd] - y[i * 8 + dd];
        s += d * d;
    }
    part[tid] = s;
    __syncthreads();
    if (tid < 8) {
        float t = 0.f;
        for (int r = 0; r < 32; ++r) t += part[r * 8 + tid];
        loss[tid] = t / (float)(B64 * HOR);
    }
}

// ---- split-phase grid barrier (system flags, spread layout, all-sweep) ----
// Best of 5 mechanisms tried (R0,R2,R3,R7,R8): plain coherent stores to one
// line per block, 128-flag sweep by wave0. Atomic-counter variants (R7/R8)
// keep lines MALL-resident but the RMW arrival path is slower net.
__device__ __forceinline__ void gbar_arrive(unsigned* dom, int rb, unsigned ep) {
    if (threadIdx.x == 0) {
        __builtin_amdgcn_s_waitcnt(0x0f70);     // vmcnt(0)
        __hip_atomic_store(dom + rb * 32, ep, __ATOMIC_RELAXED,
                           __HIP_MEMORY_SCOPE_SYSTEM);
    }
}
__device__ __forceinline__ void gbar_wait(unsigned* dom, unsigned ep) {
    const int tid = threadIdx.x;
    if (tid < 64) {
        const unsigned* f0 = dom + tid * 32;
        const unsigned* f1 = dom + (tid + 64) * 32;
        for (;;) {
            unsigned a = __hip_atomic_load(f0, __ATOMIC_RELAXED, __HIP_MEMORY_SCOPE_SYSTEM);
            unsigned b = __hip_atomic_load(f1, __ATOMIC_RELAXED, __HIP_MEMORY_SCOPE_SYSTEM);
            if (__all((a >= ep) && (b >= ep))) break;
        }
    }
    __syncthreads();
}

// ---------------- persistent recurrence kernel ----------------
// Drain-overlapped schedule (per step, 2 barriers):
//  wait A   -> h0(t) visible
//  window A: load pa/pb = h0(t) (16B sc-loads); acc += MFMA(pa/pb, Wr1h0)
//            [acc carries the h1(t-1) half from the previous window-B tail];
//            reduce; P2 cell -> publish h1(t);
//            P1(t+1) GEMM on pa/pb -> red2   [h1 store-acks drain under this]
//            arrive B
//  wait B   -> h1(t) visible
//  window B: load qa/qb = h1(t); P3 GEMM (streamed Wr2) -> reduce; P3 cell ->
//            h2x/pred; P1 cell (red2 + wih0*x) -> publish h0(t+1);
//            acc = MFMA(qa/qb, Wr1h1)        [h0 store-acks drain under this]
//            arrive A
// LDS red layout (R9): element (seg, col=n, row=m) at seg*RSEG + col*RCOL + row.
// Strides chosen so redSum's 4 lane-groups land at bank offsets {0,16,0,16}
// (2-way = free, m136) instead of the old {0,16,4,20} (4-way on 12 banks).
__global__ __launch_bounds__(256, 1) void persist_k(
    const unsigned short* __restrict__ Wp0,
    const unsigned short* __restrict__ Wp1,
    const unsigned short* __restrict__ Wp2,
    const float* __restrict__ wih0, const float* __restrict__ b0v,
    const float* __restrict__ b1v,
    const float* __restrict__ whh2, const float* __restrict__ b2v,
    const float* __restrict__ inp,
    unsigned short* __restrict__ H0a, unsigned short* __restrict__ H0b,
    unsigned short* __restrict__ H1a, unsigned short* __restrict__ H1b,
    unsigned* __restrict__ bar0, float* __restrict__ pred)
{
    const int tid = threadIdx.x;
    const int wv = tid >> 6, lane = tid & 63;
    const int blk = blockIdx.x;
    const int bg = blk & 1, rb = blk >> 1;
    const int bl = tid & 31, u = tid >> 5;
    const int mtl = bl >> 4, m16 = bl & 15;
    unsigned* dom = bar0 + (bg << 13);      // 32KB per barrier domain

    __shared__ float red1[16 * RSEG];       // ~25KB (P2 then P3)
    __shared__ float red2[16 * RSEG];       // ~25KB (P1, crosses barrier B)
    __shared__ float h2x[32 * 9];
    __shared__ ull hstage[32][3];           // 24B rows: cell u16 writes 2-way

    for (int i = tid; i < 32 * 9; i += 256) h2x[i] = 0.f;

    // ---- resident weights (Wr2 streamed per step instead) ----
    short8 Wr0[2][8], Wr1h0[2][8], Wr1h1[2][8];
    {
        const short8* p0 = (const short8*)Wp0;
        const short8* p1 = (const short8*)Wp1;
        #pragma unroll
        for (int ot = 0; ot < 2; ++ot)
            #pragma unroll
            for (int kk = 0; kk < 8; ++kk) {
                Wr0[ot][kk]   = p0[((rb * 2 + ot) * KS0 + 8 * wv + kk) * 64 + lane];
                Wr1h0[ot][kk] = p1[((rb * 2 + ot) * KS1 + 8 * wv + kk) * 64 + lane];
                Wr1h1[ot][kk] = p1[((rb * 2 + ot) * KS1 + 32 + 8 * wv + kk) * 64 + lane];
            }
    }
    float wih0r[4][8], whh2r[4][8], b0r[4], b1r[4], b2r[4];
    #pragma unroll
    for (int g = 0; g < 4; ++g) {
        int row = rb * 8 + u + 1024 * g;
        #pragma unroll
        for (int d = 0; d < 8; ++d) wih0r[g][d] = wih0[row * 8 + d];
        b0r[g] = b0v[row];
        b1r[g] = b1v[row];
        int row2 = u + 8 * g;
        #pragma unroll
        for (int d = 0; d < 8; ++d) whh2r[g][d] = whh2[row2 * 8 + d];
        b2r[g] = b2v[row2];
    }
    float c0r = 0.f, c1r = 0.f, c2r = 0.f;
    unsigned ep = 0;

    auto redWrite = [&](float* red, f32x4 (&acc)[2][2]) {
        #pragma unroll
        for (int m = 0; m < 2; ++m)
            #pragma unroll
            for (int ot = 0; ot < 2; ++ot) {
                int base = ((wv * 2 + m) * 2 + ot) * RSEG + (lane & 15) * RCOL + (lane >> 4) * 4;
                #pragma unroll
                for (int r = 0; r < 4; ++r) red[base + r] = acc[m][ot][r];
            }
    };
    auto redSum = [&](const float* red, int g) {
        int rr = u * 4 + g, ot = rr >> 4, rr16 = rr & 15;
        float s = 0.f;
        #pragma unroll
        for (int w2i = 0; w2i < 4; ++w2i)
            s += red[((w2i * 2 + mtl) * 2 + ot) * RSEG + rr16 * RCOL + m16];
        return s;
    };
    auto hPublish = [&](unsigned short* Hw) {
        __syncthreads();
        if (tid < 32) {
            int b = bg * 32 + tid;
            int chunk = ((b >> 4) * KS0 + (rb >> 2)) * 64 + ((b & 15) | ((rb & 3) << 4));
            cstore16((unsigned short*)((ull*)Hw + chunk * 2),
                     hstage[tid][0], hstage[tid][1]);
        }
    };

    __syncthreads();

    // acc carries the P2 h1-half GEMM across the A barrier; h1(-1)=0 -> zero
    f32x4 acc[2][2];
    #pragma unroll
    for (int m = 0; m < 2; ++m)
        #pragma unroll
        for (int ot = 0; ot < 2; ++ot) acc[m][ot] = (f32x4){0.f, 0.f, 0.f, 0.f};

    // ---- preamble: P1(0) (h0(-1)=0 -> GEMM term vanishes) ----
    {
        float xv[8];
        int b = bg * 32 + bl;
        #pragma unroll
        for (int d = 0; d < 8; ++d) xv[d] = inp[(b * TT + 0) * DD + d];
        float g4[4];
        #pragma unroll
        for (int g = 0; g < 4; ++g) {
            float s = b0r[g];
            #pragma unroll
            for (int d = 0; d < 8; ++d) s += wih0r[g][d] * xv[d];
            g4[g] = s;
        }
        c0r = sigm(g4[0]) * ftanh(g4[2]);
        float hn = sigm(g4[3]) * ftanh(c0r);
        ((unsigned short*)hstage)[bl * 12 + u] = f2bf(hn);
        hPublish(H0a);                               // h0(0)
    }
    gbar_arrive(dom, rb, ++ep);

    for (int t = 0; t < NSTEP; ++t) {
        const int par = t & 1;
        const unsigned short* H0cur = par ? H0b : H0a;   // h0(t)
        unsigned short* H1w = par ? H1b : H1a;           // h1(t) dest
        unsigned short* H0nxt = par ? H0a : H0b;         // h0(t+1) dest
        const bool last = (t == NSTEP - 1);

        gbar_wait(dom, ep);                  // wait A: h0(t) visible

        // ================= window A =================
        short8 pa[8], pb[8];
        {
            #pragma unroll
            for (int kk = 0; kk < 8; ++kk) {
                pa[kk] = cload16(H0cur + (((bg * 2 + 0) * KS0 + 8 * wv + kk) * 64 + lane) * 8);
                pb[kk] = cload16(H0cur + (((bg * 2 + 1) * KS0 + 8 * wv + kk) * 64 + lane) * 8);
            }
            kwait();
            #pragma unroll
            for (int kk = 0; kk < 8; ++kk) {
                #pragma unroll
                for (int ot = 0; ot < 2; ++ot) {
                    acc[0][ot] = __builtin_amdgcn_mfma_f32_16x16x32_bf16(pa[kk], Wr1h0[ot][kk], acc[0][ot], 0, 0, 0);
                    acc[1][ot] = __builtin_amdgcn_mfma_f32_16x16x32_bf16(pb[kk], Wr1h0[ot][kk], acc[1][ot], 0, 0, 0);
                }
            }
            redWrite(red1, acc);
            __syncthreads();
            float g4[4];
            #pragma unroll
            for (int g = 0; g < 4; ++g) g4[g] = b1r[g] + redSum(red1, g);
            c1r = sigm(g4[1]) * c1r + sigm(g4[0]) * ftanh(g4[2]);
            float hn = sigm(g4[3]) * ftanh(c1r);
            ((unsigned short*)hstage)[bl * 12 + u] = f2bf(hn);
            hPublish(H1w);                               // h1(t)
        }

        // ---- gap B BEFORE arrive B: h1 store-acks drain under this GEMM ----
        if (!last) {
            f32x4 a1[2][2];
            #pragma unroll
            for (int m = 0; m < 2; ++m)
                #pragma unroll
                for (int ot = 0; ot < 2; ++ot) a1[m][ot] = (f32x4){0.f, 0.f, 0.f, 0.f};
            #pragma unroll
            for (int kk = 0; kk < 8; ++kk) {
                #pragma unroll
                for (int ot = 0; ot < 2; ++ot) {
                    a1[0][ot] = __builtin_amdgcn_mfma_f32_16x16x32_bf16(pa[kk], Wr0[ot][kk], a1[0][ot], 0, 0, 0);
                    a1[1][ot] = __builtin_amdgcn_mfma_f32_16x16x32_bf16(pb[kk], Wr0[ot][kk], a1[1][ot], 0, 0, 0);
                }
            }
            redWrite(red2, a1);
        }
        gbar_arrive(dom, rb, ++ep);          // arrive B
        gbar_wait(dom, ep);                  // wait B: h1(t) visible

        // ================= window B =================
        {
            // stream Wr2 (L1/L2-cached, immutable) alongside the h1 loads
            const short8* p2w = (const short8*)Wp2;
            short8 w2[2][8];
            #pragma unroll
            for (int ot = 0; ot < 2; ++ot)
                #pragma unroll
                for (int kk = 0; kk < 8; ++kk)
                    w2[ot][kk] = p2w[(ot * KS0 + 8 * wv + kk) * 64 + lane];
            short8 qa[8], qb[8];
            #pragma unroll
            for (int kk = 0; kk < 8; ++kk) {
                qa[kk] = cload16(H1w + (((bg * 2 + 0) * KS0 + 8 * wv + kk) * 64 + lane) * 8);
                qb[kk] = cload16(H1w + (((bg * 2 + 1) * KS0 + 8 * wv + kk) * 64 + lane) * 8);
            }
            kwait();
            f32x4 a3[2][2];
            #pragma unroll
            for (int m = 0; m < 2; ++m)
                #pragma unroll
                for (int ot = 0; ot < 2; ++ot) a3[m][ot] = (f32x4){0.f, 0.f, 0.f, 0.f};
            #pragma unroll
            for (int kk = 0; kk < 8; ++kk) {
                #pragma unroll
                for (int ot = 0; ot < 2; ++ot) {
                    a3[0][ot] = __builtin_amdgcn_mfma_f32_16x16x32_bf16(qa[kk], w2[ot][kk], a3[0][ot], 0, 0, 0);
                    a3[1][ot] = __builtin_amdgcn_mfma_f32_16x16x32_bf16(qb[kk], w2[ot][kk], a3[1][ot], 0, 0, 0);
                }
            }
            redWrite(red1, a3);             // red1 free since window A's redSum
            __syncthreads();
            // P3 cell
            float xo[8];
            #pragma unroll
            for (int d = 0; d < 8; ++d) xo[d] = h2x[bl * 9 + d];
            float g4[4];
            #pragma unroll
            for (int g = 0; g < 4; ++g) {
                float s = b2r[g] + redSum(red1, g);
                #pragma unroll
                for (int d = 0; d < 8; ++d) s += whh2r[g][d] * xo[d];
                g4[g] = s;
            }
            float cn = sigm(g4[1]) * c2r + sigm(g4[0]) * ftanh(g4[2]);
            c2r = cn;
            float hn2 = sigm(g4[3]) * ftanh(cn);
            __syncthreads();                // old-h2x reads done
            h2x[bl * 9 + u] = hn2;
            if (rb == 0 && t >= ENC - 1)
                pred[((bg * 32 + bl) * HOR + (t - (ENC - 1))) * DD + u] = hn2;

            if (!last) {
                __syncthreads();            // h2x(t) visible
                const int tt = t + 1;
                float xv[8];
                if (tt < ENC) {
                    int b = bg * 32 + bl;
                    #pragma unroll
                    for (int d = 0; d < 8; ++d) xv[d] = inp[(b * TT + tt) * DD + d];
                } else {
                    #pragma unroll
                    for (int d = 0; d < 8; ++d) xv[d] = h2x[bl * 9 + d];
                }
                float g1[4];
                #pragma unroll
                for (int g = 0; g < 4; ++g) {
                    float s = b0r[g] + redSum(red2, g);
                    #pragma unroll
                    for (int d = 0; d < 8; ++d) s += wih0r[g][d] * xv[d];
                    g1[g] = s;
                }
                c0r = sigm(g1[1]) * c0r + sigm(g1[0]) * ftanh(g1[2]);
                float hn0 = sigm(g1[3]) * ftanh(c0r);
                ((unsigned short*)hstage)[bl * 12 + u] = f2bf(hn0);
                hPublish(H0nxt);                          // h0(t+1)

                // ---- gap A for t+1 BEFORE arrive A: h0 store-acks drain
                // under this GEMM; result carried in acc across the barrier.
                #pragma unroll
                for (int m = 0; m < 2; ++m)
                    #pragma unroll
                    for (int ot = 0; ot < 2; ++ot) acc[m][ot] = (f32x4){0.f, 0.f, 0.f, 0.f};
                #pragma unroll
                for (int kk = 0; kk < 8; ++kk) {
                    #pragma unroll
                    for (int ot = 0; ot < 2; ++ot) {
                        acc[0][ot] = __builtin_amdgcn_mfma_f32_16x16x32_bf16(qa[kk], Wr1h1[ot][kk], acc[0][ot], 0, 0, 0);
                        acc[1][ot] = __builtin_amdgcn_mfma_f32_16x16x32_bf16(qb[kk], Wr1h1[ot][kk], acc[1][ot], 0, 0, 0);
                    }
                }
                gbar_arrive(dom, rb, ++ep);               // arrive A
            }
        }
    }
}

// ---------------- host ----------------

extern "C" void kernel_launch(void* const* d_in, const int* in_sizes, int n_in,
                              void* d_out, int out_size, void* d_ws, size_t ws_size,
                              hipStream_t stream)
{
    const float* inp  = (const float*)d_in[0];
    const float* wih0 = (const float*)d_in[1];
    const float* whh0 = (const float*)d_in[2];
    const float* b0v  = (const float*)d_in[3];
    const float* wih1 = (const float*)d_in[4];
    const float* whh1 = (const float*)d_in[5];
    const float* b1v  = (const float*)d_in[6];
    const float* wih2 = (const float*)d_in[7];
    const float* whh2 = (const float*)d_in[8];
    const float* b2v  = (const float*)d_in[9];
    float* out = (float*)d_out;   // pred[172032] | y[172032] | loss[8]

    char* base = (char*)d_ws;
    size_t off = 0;
    auto carve = [&](size_t bytes) -> void* {
        void* p = base + off;
        off += (bytes + 255) & ~((size_t)255);
        return p;
    };
    unsigned short* Wp0 = (unsigned short*)carve((size_t)128 * 2 * KS0 * 64 * 8 * 2);
    unsigned short* Wp1 = (unsigned short*)carve((size_t)128 * 2 * KS1 * 64 * 8 * 2);
    unsigned short* Wp2 = (unsigned short*)carve((size_t)2 * KS0 * 64 * 8 * 2);
    size_t state_off = off;
    unsigned short* H0a = (unsigned short*)carve(B64 * H * 2);
    unsigned short* H0b = (unsigned short*)carve(B64 * H * 2);
    unsigned short* H1a = (unsigned short*)carve(B64 * H * 2);
    unsigned short* H1b = (unsigned short*)carve(B64 * H * 2);
    unsigned* bar = (unsigned*)carve(2 * 8192 * 4);   // 2 domains x 32KB
    size_t state_bytes = off - state_off;
    if (off > ws_size) return;

    zero_k<<<64, 256, 0, stream>>>((unsigned int*)(base + state_off), (int)(state_bytes / 4));
    pack0_k<<<2048, 256, 0, stream>>>(whh0, Wp0);
    pack1_k<<<4096, 256, 0, stream>>>(wih1, whh1, Wp1);
    pack2_k<<<32, 256, 0, stream>>>(wih2, Wp2);
    copy_y_k<<<672, 256, 0, stream>>>(inp, out + 172032);

    persist_k<<<NBLK, 256, 0, stream>>>(Wp0, Wp1, Wp2, wih0, b0v, b1v, whh2, b2v,
                                        inp, H0a, H0b, H1a, H1b, bar, out);

    loss_k<<<1, 256, 0, stream>>>(out, out + 172032, out + 344064);
}

// Round 11
// 3292.895 us; speedup vs baseline: 1.2790x; 1.0579x over previous
//
#include <hip/hip_runtime.h>
#include <math.h>

#define B64 64
#define H 1024
#define DD 8
#define ENC 96
#define HOR 336
#define TT 432
#define NSTEP 431
#define NBLK 256
#define KS0 32      // K=1024 in 32-wide chunks
#define KS1 64      // K=2048
#define RSEG 440    // red segment stride (words): 2*RSEG%32=16 -> mtl groups +16
#define RCOL 28     // red column stride (words): write starts cover all 32 banks
                    // (8 words/bank = wave64-b128 minimum); 4*28%32=16 -> reads 2-way

typedef __attribute__((ext_vector_type(8))) short short8;
typedef __attribute__((ext_vector_type(4))) float f32x4;
typedef __attribute__((ext_vector_type(4))) unsigned int u32x4;
typedef unsigned long long ull;

__device__ __forceinline__ unsigned short f2bf(float x) {
    union { float f; unsigned u; } v; v.f = x;
    unsigned r = v.u + 0x7fffu + ((v.u >> 16) & 1u);
    return (unsigned short)(r >> 16);
}
__device__ __forceinline__ float sigm(float x) {
    return __builtin_amdgcn_rcpf(1.0f + __expf(-x));
}
__device__ __forceinline__ float ftanh(float x) {
    float e = __expf(fminf(x, 10.0f) * 2.0f);   // clamp: avoid inf/inf
    return (e - 1.0f) * __builtin_amdgcn_rcpf(e + 1.0f);
}

// Agent-coherent 16B load/store via one dwordx4 (sc0 sc1) — halves coherent
// transaction count vs 2x8B atomics. Callers MUST kwait() before using loads.
__device__ __forceinline__ short8 cload16(const unsigned short* p) {
    u32x4 v;
    asm volatile("global_load_dwordx4 %0, %1, off sc0 sc1"
                 : "=v"(v) : "v"(p) : "memory");
    union { u32x4 u; short8 s; } c; c.u = v; return c.s;
}
__device__ __forceinline__ void cstore16(unsigned short* p, ull lo, ull hi) {
    union { ull u[2]; u32x4 v; } c; c.u[0] = lo; c.u[1] = hi;
    asm volatile("global_store_dwordx4 %0, %1, off sc0 sc1"
                 :: "v"(p), "v"(c.v) : "memory");
}
__device__ __forceinline__ void kwait() {
    asm volatile("s_waitcnt vmcnt(0)" ::: "memory");
    __builtin_amdgcn_sched_barrier(0);      // guide rule 18: pin uses after wait
}

// ---------------- fused prep kernel (5 independent jobs, disjoint outputs) ----------------

__global__ void prep_k(const float* __restrict__ whh0,
                       const float* __restrict__ wih1, const float* __restrict__ whh1,
                       const float* __restrict__ wih2, const float* __restrict__ inp,
                       unsigned short* __restrict__ Wp0, unsigned short* __restrict__ Wp1,
                       unsigned short* __restrict__ Wp2, float* __restrict__ y,
                       unsigned int* __restrict__ zp, int zn, float* __restrict__ loss)
{
    const int stride = gridDim.x * 256;
    const int base = blockIdx.x * 256 + threadIdx.x;

    // zero state + barriers (+ loss accumulators)
    for (int i = base; i < zn; i += stride) zp[i] = 0u;
    if (base < 8) loss[base] = 0.f;

    // pack0: whh0 -> Wp0
    {
        const int total = 128 * 2 * KS0 * 64 * 8;
        for (int idx = base; idx < total; idx += stride) {
            int j = idx & 7, lane = (idx >> 3) & 63, ks = (idx >> 9) & 31, nt = (idx >> 14) & 1, nb = idx >> 15;
            int rr = nt * 16 + (lane & 15);
            int row = nb * 8 + (rr >> 2) + 1024 * (rr & 3);
            int k = ks * 32 + ((lane >> 4) << 3) + j;
            Wp0[idx] = f2bf(whh0[row * 1024 + k]);
        }
    }
    // pack1: wih1|whh1 -> Wp1
    {
        const int total = 128 * 2 * KS1 * 64 * 8;
        for (int idx = base; idx < total; idx += stride) {
            int j = idx & 7, lane = (idx >> 3) & 63, ks = (idx >> 9) & 63, nt = (idx >> 15) & 1, nb = idx >> 16;
            int rr = nt * 16 + (lane & 15);
            int row = nb * 8 + (rr >> 2) + 1024 * (rr & 3);
            int k = ks * 32 + ((lane >> 4) << 3) + j;
            float v = (k < 1024) ? wih1[row * 1024 + k] : whh1[row * 1024 + (k - 1024)];
            Wp1[idx] = f2bf(v);
        }
    }
    // pack2: wih2 -> Wp2
    {
        const int total = 2 * KS0 * 64 * 8;
        for (int idx = base; idx < total; idx += stride) {
            int j = idx & 7, lane = (idx >> 3) & 63, ks = (idx >> 9) & 31, nt = (idx >> 14) & 1;
            int rr = nt * 16 + (lane & 15);
            int row = (rr >> 2) + 8 * (rr & 3);
            int k = ks * 32 + ((lane >> 4) << 3) + j;
            Wp2[idx] = f2bf(wih2[row * 1024 + k]);
        }
    }
    // copy_y: inp horizon slice -> y
    {
        const int total = B64 * HOR * DD;
        for (int i = base; i < total; i += stride) {
            int b = i / (HOR * DD);
            int rem = i - b * (HOR * DD);
            y[i] = inp[b * (TT * DD) + ENC * DD + rem];
        }
    }
}

// parallel loss: 64 blocks, per-block partial -> scaled atomicAdd (fp reorder
// error ~1e-7 << 2.4e-4 tolerance)
__global__ void loss_k(const float* __restrict__ pred, const float* __restrict__ y,
                       float* __restrict__ loss) {
    __shared__ float part[256];
    int tid = threadIdx.x;
    int dd = tid & 7, cc = tid >> 3;
    float s = 0.f;
    for (int i = blockIdx.x * 32 + cc; i < B64 * HOR; i += 64 * 32) {
        float d = pred[i * 8 + dd] - y[i * 8 + dd];
        s += d * d;
    }
    part[tid] = s;
    __syncthreads();
    if (tid < 8) {
        float t = 0.f;
        for (int r = 0; r < 32; ++r) t += part[r * 8 + tid];
        atomicAdd(&loss[tid], t * (1.0f / (float)(B64 * HOR)));
    }
}

// ---- split-phase grid barrier (system flags, spread layout, all-sweep) ----
// Best of 6 mechanisms tried (R0,R2,R3,R4,R7,R8): plain coherent stores to one
// line per block, 128-flag sweep by wave0. Atomic-counter variants (R7/R8)
// keep lines MALL-resident but the RMW arrival path is slower net.
__device__ __forceinline__ void gbar_arrive(unsigned* dom, int rb, unsigned ep) {
    if (threadIdx.x == 0) {
        __builtin_amdgcn_s_waitcnt(0x0f70);     // vmcnt(0)
        __hip_atomic_store(dom + rb * 32, ep, __ATOMIC_RELAXED,
                           __HIP_MEMORY_SCOPE_SYSTEM);
    }
}
__device__ __forceinline__ void gbar_wait(unsigned* dom, unsigned ep) {
    const int tid = threadIdx.x;
    if (tid < 64) {
        const unsigned* f0 = dom + tid * 32;
        const unsigned* f1 = dom + (tid + 64) * 32;
        for (;;) {
            unsigned a = __hip_atomic_load(f0, __ATOMIC_RELAXED, __HIP_MEMORY_SCOPE_SYSTEM);
            unsigned b = __hip_atomic_load(f1, __ATOMIC_RELAXED, __HIP_MEMORY_SCOPE_SYSTEM);
            if (__all((a >= ep) && (b >= ep))) break;
        }
    }
    __syncthreads();
}

// ---------------- persistent recurrence kernel ----------------
// Drain-overlapped schedule (per step, 2 barriers):
//  wait A   -> h0(t) visible
//  window A: load pa/pb = h0(t) (16B sc-loads); acc += MFMA(pa/pb, Wr1h0)
//            [acc carries the h1(t-1) half from the previous window-B tail];
//            reduce; P2 cell -> publish h1(t);
//            P1(t+1) GEMM on pa/pb -> red2   [h1 store-acks drain under this]
//            arrive B
//  wait B   -> h1(t) visible
//  window B: load qa/qb = h1(t); P3 GEMM (streamed Wr2) -> reduce; P3 cell ->
//            h2x/pred; P1 cell (red2 + wih0*x) -> publish h0(t+1);
//            acc = MFMA(qa/qb, Wr1h1)        [h0 store-acks drain under this]
//            arrive A
// LDS red layout (R9/R10): elem (seg,col,row) at seg*RSEG + col*RCOL + row.
// RCOL=28/RSEG=440: redSum reads 2-way (free) AND redWrite b128 stores at the
// wave64 minimum (8 words/bank across all 32 banks).
__global__ __launch_bounds__(256, 1) void persist_k(
    const unsigned short* __restrict__ Wp0,
    const unsigned short* __restrict__ Wp1,
    const unsigned short* __restrict__ Wp2,
    const float* __restrict__ wih0, const float* __restrict__ b0v,
    const float* __restrict__ b1v,
    const float* __restrict__ whh2, const float* __restrict__ b2v,
    const float* __restrict__ inp,
    unsigned short* __restrict__ H0a, unsigned short* __restrict__ H0b,
    unsigned short* __restrict__ H1a, unsigned short* __restrict__ H1b,
    unsigned* __restrict__ bar0, float* __restrict__ pred)
{
    const int tid = threadIdx.x;
    const int wv = tid >> 6, lane = tid & 63;
    const int blk = blockIdx.x;
    const int bg = blk & 1, rb = blk >> 1;
    const int bl = tid & 31, u = tid >> 5;
    const int mtl = bl >> 4, m16 = bl & 15;
    unsigned* dom = bar0 + (bg << 13);      // 32KB per barrier domain

    __shared__ float red1[16 * RSEG];       // ~27.5KB (P2 then P3)
    __shared__ float red2[16 * RSEG];       // ~27.5KB (P1, crosses barrier B)
    __shared__ float h2x[32 * 9];
    __shared__ ull hstage[32][3];           // 24B rows: cell u16 writes 2-way

    for (int i = tid; i < 32 * 9; i += 256) h2x[i] = 0.f;

    // ---- resident weights (Wr2 streamed per step instead) ----
    short8 Wr0[2][8], Wr1h0[2][8], Wr1h1[2][8];
    {
        const short8* p0 = (const short8*)Wp0;
        const short8* p1 = (const short8*)Wp1;
        #pragma unroll
        for (int ot = 0; ot < 2; ++ot)
            #pragma unroll
            for (int kk = 0; kk < 8; ++kk) {
                Wr0[ot][kk]   = p0[((rb * 2 + ot) * KS0 + 8 * wv + kk) * 64 + lane];
                Wr1h0[ot][kk] = p1[((rb * 2 + ot) * KS1 + 8 * wv + kk) * 64 + lane];
                Wr1h1[ot][kk] = p1[((rb * 2 + ot) * KS1 + 32 + 8 * wv + kk) * 64 + lane];
            }
    }
    float wih0r[4][8], whh2r[4][8], b0r[4], b1r[4], b2r[4];
    #pragma unroll
    for (int g = 0; g < 4; ++g) {
        int row = rb * 8 + u + 1024 * g;
        #pragma unroll
        for (int d = 0; d < 8; ++d) wih0r[g][d] = wih0[row * 8 + d];
        b0r[g] = b0v[row];
        b1r[g] = b1v[row];
        int row2 = u + 8 * g;
        #pragma unroll
        for (int d = 0; d < 8; ++d) whh2r[g][d] = whh2[row2 * 8 + d];
        b2r[g] = b2v[row2];
    }
    float c0r = 0.f, c1r = 0.f, c2r = 0.f;
    unsigned ep = 0;

    auto redWrite = [&](float* red, f32x4 (&acc)[2][2]) {
        #pragma unroll
        for (int m = 0; m < 2; ++m)
            #pragma unroll
            for (int ot = 0; ot < 2; ++ot) {
                int base = ((wv * 2 + m) * 2 + ot) * RSEG + (lane & 15) * RCOL + (lane >> 4) * 4;
                #pragma unroll
                for (int r = 0; r < 4; ++r) red[base + r] = acc[m][ot][r];
            }
    };
    auto redSum = [&](const float* red, int g) {
        int rr = u * 4 + g, ot = rr >> 4, rr16 = rr & 15;
        float s = 0.f;
        #pragma unroll
        for (int w2i = 0; w2i < 4; ++w2i)
            s += red[((w2i * 2 + mtl) * 2 + ot) * RSEG + rr16 * RCOL + m16];
        return s;
    };
    auto hPublish = [&](unsigned short* Hw) {
        __syncthreads();
        if (tid < 32) {
            int b = bg * 32 + tid;
            int chunk = ((b >> 4) * KS0 + (rb >> 2)) * 64 + ((b & 15) | ((rb & 3) << 4));
            cstore16((unsigned short*)((ull*)Hw + chunk * 2),
                     hstage[tid][0], hstage[tid][1]);
        }
    };

    __syncthreads();

    // acc carries the P2 h1-half GEMM across the A barrier; h1(-1)=0 -> zero
    f32x4 acc[2][2];
    #pragma unroll
    for (int m = 0; m < 2; ++m)
        #pragma unroll
        for (int ot = 0; ot < 2; ++ot) acc[m][ot] = (f32x4){0.f, 0.f, 0.f, 0.f};

    // ---- preamble: P1(0) (h0(-1)=0 -> GEMM term vanishes) ----
    {
        float xv[8];
        int b = bg * 32 + bl;
        #pragma unroll
        for (int d = 0; d < 8; ++d) xv[d] = inp[(b * TT + 0) * DD + d];
        float g4[4];
        #pragma unroll
        for (int g = 0; g < 4; ++g) {
            float s = b0r[g];
            #pragma unroll
            for (int d = 0; d < 8; ++d) s += wih0r[g][d] * xv[d];
            g4[g] = s;
        }
        c0r = sigm(g4[0]) * ftanh(g4[2]);
        float hn = sigm(g4[3]) * ftanh(c0r);
        ((unsigned short*)hstage)[bl * 12 + u] = f2bf(hn);
        hPublish(H0a);                               // h0(0)
    }
    gbar_arrive(dom, rb, ++ep);

    for (int t = 0; t < NSTEP; ++t) {
        const int par = t & 1;
        const unsigned short* H0cur = par ? H0b : H0a;   // h0(t)
        unsigned short* H1w = par ? H1b : H1a;           // h1(t) dest
        unsigned short* H0nxt = par ? H0a : H0b;         // h0(t+1) dest
        const bool last = (t == NSTEP - 1);

        gbar_wait(dom, ep);                  // wait A: h0(t) visible

        // ================= window A =================
        short8 pa[8], pb[8];
        {
            #pragma unroll
            for (int kk = 0; kk < 8; ++kk) {
                pa[kk] = cload16(H0cur + (((bg * 2 + 0) * KS0 + 8 * wv + kk) * 64 + lane) * 8);
                pb[kk] = cload16(H0cur + (((bg * 2 + 1) * KS0 + 8 * wv + kk) * 64 + lane) * 8);
            }
            kwait();
            #pragma unroll
            for (int kk = 0; kk < 8; ++kk) {
                #pragma unroll
                for (int ot = 0; ot < 2; ++ot) {
                    acc[0][ot] = __builtin_amdgcn_mfma_f32_16x16x32_bf16(pa[kk], Wr1h0[ot][kk], acc[0][ot], 0, 0, 0);
                    acc[1][ot] = __builtin_amdgcn_mfma_f32_16x16x32_bf16(pb[kk], Wr1h0[ot][kk], acc[1][ot], 0, 0, 0);
                }
            }
            redWrite(red1, acc);
            __syncthreads();
            float g4[4];
            #pragma unroll
            for (int g = 0; g < 4; ++g) g4[g] = b1r[g] + redSum(red1, g);
            c1r = sigm(g4[1]) * c1r + sigm(g4[0]) * ftanh(g4[2]);
            float hn = sigm(g4[3]) * ftanh(c1r);
            ((unsigned short*)hstage)[bl * 12 + u] = f2bf(hn);
            hPublish(H1w);                               // h1(t)
        }

        // ---- gap B BEFORE arrive B: h1 store-acks drain under this GEMM ----
        if (!last) {
            f32x4 a1[2][2];
            #pragma unroll
            for (int m = 0; m < 2; ++m)
                #pragma unroll
                for (int ot = 0; ot < 2; ++ot) a1[m][ot] = (f32x4){0.f, 0.f, 0.f, 0.f};
            #pragma unroll
            for (int kk = 0; kk < 8; ++kk) {
                #pragma unroll
                for (int ot = 0; ot < 2; ++ot) {
                    a1[0][ot] = __builtin_amdgcn_mfma_f32_16x16x32_bf16(pa[kk], Wr0[ot][kk], a1[0][ot], 0, 0, 0);
                    a1[1][ot] = __builtin_amdgcn_mfma_f32_16x16x32_bf16(pb[kk], Wr0[ot][kk], a1[1][ot], 0, 0, 0);
                }
            }
            redWrite(red2, a1);
        }
        gbar_arrive(dom, rb, ++ep);          // arrive B
        gbar_wait(dom, ep);                  // wait B: h1(t) visible

        // ================= window B =================
        {
            // stream Wr2 (L1/L2-cached, immutable) alongside the h1 loads
            const short8* p2w = (const short8*)Wp2;
            short8 w2[2][8];
            #pragma unroll
            for (int ot = 0; ot < 2; ++ot)
                #pragma unroll
                for (int kk = 0; kk < 8; ++kk)
                    w2[ot][kk] = p2w[(ot * KS0 + 8 * wv + kk) * 64 + lane];
            short8 qa[8], qb[8];
            #pragma unroll
            for (int kk = 0; kk < 8; ++kk) {
                qa[kk] = cload16(H1w + (((bg * 2 + 0) * KS0 + 8 * wv + kk) * 64 + lane) * 8);
                qb[kk] = cload16(H1w + (((bg * 2 + 1) * KS0 + 8 * wv + kk) * 64 + lane) * 8);
            }
            kwait();
            f32x4 a3[2][2];
            #pragma unroll
            for (int m = 0; m < 2; ++m)
                #pragma unroll
                for (int ot = 0; ot < 2; ++ot) a3[m][ot] = (f32x4){0.f, 0.f, 0.f, 0.f};
            #pragma unroll
            for (int kk = 0; kk < 8; ++kk) {
                #pragma unroll
                for (int ot = 0; ot < 2; ++ot) {
                    a3[0][ot] = __builtin_amdgcn_mfma_f32_16x16x32_bf16(qa[kk], w2[ot][kk], a3[0][ot], 0, 0, 0);
                    a3[1][ot] = __builtin_amdgcn_mfma_f32_16x16x32_bf16(qb[kk], w2[ot][kk], a3[1][ot], 0, 0, 0);
                }
            }
            redWrite(red1, a3);             // red1 free since window A's redSum
            __syncthreads();
            // P3 cell
            float xo[8];
            #pragma unroll
            for (int d = 0; d < 8; ++d) xo[d] = h2x[bl * 9 + d];
            float g4[4];
            #pragma unroll
            for (int g = 0; g < 4; ++g) {
                float s = b2r[g] + redSum(red1, g);
                #pragma unroll
                for (int d = 0; d < 8; ++d) s += whh2r[g][d] * xo[d];
                g4[g] = s;
            }
            float cn = sigm(g4[1]) * c2r + sigm(g4[0]) * ftanh(g4[2]);
            c2r = cn;
            float hn2 = sigm(g4[3]) * ftanh(cn);
            __syncthreads();                // old-h2x reads done
            h2x[bl * 9 + u] = hn2;
            if (rb == 0 && t >= ENC - 1)
                pred[((bg * 32 + bl) * HOR + (t - (ENC - 1))) * DD + u] = hn2;

            if (!last) {
                __syncthreads();            // h2x(t) visible
                const int tt = t + 1;
                float xv[8];
                if (tt < ENC) {
                    int b = bg * 32 + bl;
                    #pragma unroll
                    for (int d = 0; d < 8; ++d) xv[d] = inp[(b * TT + tt) * DD + d];
                } else {
                    #pragma unroll
                    for (int d = 0; d < 8; ++d) xv[d] = h2x[bl * 9 + d];
                }
                float g1[4];
                #pragma unroll
                for (int g = 0; g < 4; ++g) {
                    float s = b0r[g] + redSum(red2, g);
                    #pragma unroll
                    for (int d = 0; d < 8; ++d) s += wih0r[g][d] * xv[d];
                    g1[g] = s;
                }
                c0r = sigm(g1[1]) * c0r + sigm(g1[0]) * ftanh(g1[2]);
                float hn0 = sigm(g1[3]) * ftanh(c0r);
                ((unsigned short*)hstage)[bl * 12 + u] = f2bf(hn0);
                hPublish(H0nxt);                          // h0(t+1)

                // ---- gap A for t+1 BEFORE arrive A: h0 store-acks drain
                // under this GEMM; result carried in acc across the barrier.
                #pragma unroll
                for (int m = 0; m < 2; ++m)
                    #pragma unroll
                    for (int ot = 0; ot < 2; ++ot) acc[m][ot] = (f32x4){0.f, 0.f, 0.f, 0.f};
                #pragma unroll
                for (int kk = 0; kk < 8; ++kk) {
                    #pragma unroll
                    for (int ot = 0; ot < 2; ++ot) {
                        acc[0][ot] = __builtin_amdgcn_mfma_f32_16x16x32_bf16(qa[kk], Wr1h1[ot][kk], acc[0][ot], 0, 0, 0);
                        acc[1][ot] = __builtin_amdgcn_mfma_f32_16x16x32_bf16(qb[kk], Wr1h1[ot][kk], acc[1][ot], 0, 0, 0);
                    }
                }
                gbar_arrive(dom, rb, ++ep);               // arrive A
            }
        }
    }
}

// ---------------- host ----------------

extern "C" void kernel_launch(void* const* d_in, const int* in_sizes, int n_in,
                              void* d_out, int out_size, void* d_ws, size_t ws_size,
                              hipStream_t stream)
{
    const float* inp  = (const float*)d_in[0];
    const float* wih0 = (const float*)d_in[1];
    const float* whh0 = (const float*)d_in[2];
    const float* b0v  = (const float*)d_in[3];
    const float* wih1 = (const float*)d_in[4];
    const float* whh1 = (const float*)d_in[5];
    const float* b1v  = (const float*)d_in[6];
    const float* wih2 = (const float*)d_in[7];
    const float* whh2 = (const float*)d_in[8];
    const float* b2v  = (const float*)d_in[9];
    float* out = (float*)d_out;   // pred[172032] | y[172032] | loss[8]

    char* base = (char*)d_ws;
    size_t off = 0;
    auto carve = [&](size_t bytes) -> void* {
        void* p = base + off;
        off += (bytes + 255) & ~((size_t)255);
        return p;
    };
    unsigned short* Wp0 = (unsigned short*)carve((size_t)128 * 2 * KS0 * 64 * 8 * 2);
    unsigned short* Wp1 = (unsigned short*)carve((size_t)128 * 2 * KS1 * 64 * 8 * 2);
    unsigned short* Wp2 = (unsigned short*)carve((size_t)2 * KS0 * 64 * 8 * 2);
    size_t state_off = off;
    unsigned short* H0a = (unsigned short*)carve(B64 * H * 2);
    unsigned short* H0b = (unsigned short*)carve(B64 * H * 2);
    unsigned short* H1a = (unsigned short*)carve(B64 * H * 2);
    unsigned short* H1b = (unsigned short*)carve(B64 * H * 2);
    unsigned* bar = (unsigned*)carve(2 * 8192 * 4);   // 2 domains x 32KB
    size_t state_bytes = off - state_off;
    if (off > ws_size) return;

    prep_k<<<2048, 256, 0, stream>>>(whh0, wih1, whh1, wih2, inp,
                                     Wp0, Wp1, Wp2, out + 172032,
                                     (unsigned int*)(base + state_off),
                                     (int)(state_bytes / 4), out + 344064);

    persist_k<<<NBLK, 256, 0, stream>>>(Wp0, Wp1, Wp2, wih0, b0v, b1v, whh2, b2v,
                                        inp, H0a, H0b, H1a, H1b, bar, out);

    loss_k<<<64, 256, 0, stream>>>(out, out + 172032, out + 344064);
}